// Round 8
// baseline (440.860 us; speedup 1.0000x reference)
//
#include <hip/hip_runtime.h>
#include <hip/hip_bf16.h>

#define NN 50000
#define NE 1200000
#define D 64
#define NEG_SLOPE 0.2f
#define EPS_SM 1e-16f
#define EPS_LN 1e-5f
#define KMAX 4            // supports degree <= 256; Poisson(24) max over 50k nodes ~55
#define BSH 6             // 64 nodes per bucket
#define NBUK 782          // ceil(50000/64)
#define BCAP 2048         // fixed bucket capacity (mean 1536, +13 sigma)
#define BCAPSH 11
#define EPB 4096          // edges per partition block
#define NPB 293           // ceil(NE/EPB)
#define GP_NODES 32
#define GP_BLOCKS 1563    // ceil(50000/32)
#define GAT_BLOCKS 12500  // NN/4 exactly

__device__ __forceinline__ float waveReduceSum(float v) {
    #pragma unroll
    for (int off = 32; off > 0; off >>= 1)
        v += __shfl_xor(v, off, 64);
    return v;
}
__device__ __forceinline__ float waveReduceMax(float v) {
    #pragma unroll
    for (int off = 32; off > 0; off >>= 1)
        v = fmaxf(v, __shfl_xor(v, off, 64));
    return v;
}
__device__ __forceinline__ float bflo(unsigned v) { return __uint_as_float(v << 16); }
__device__ __forceinline__ float bfhi(unsigned v) { return __uint_as_float(v & 0xffff0000u); }

// ---------------------------------------------------------------------------
// Per-node projections + attention logits. 32 nodes/block, 8 nodes/wave.
// ---------------------------------------------------------------------------
template <bool HASD>
__global__ __launch_bounds__(256) void gemm_proj(
                          const float* __restrict__ hin,
                          const float* __restrict__ Wsrc,
                          const float* __restrict__ Wdst,
                          const float* __restrict__ Wlin,
                          const float* __restrict__ avs,
                          const float* __restrict__ avd,
                          const float* __restrict__ bgat,
                          const float* __restrict__ blin,
                          __hip_bfloat16* __restrict__ hp,
                          float* __restrict__ agg,
                          float* __restrict__ alpha_s,
                          float* __restrict__ alpha_d) {
    __shared__ float xt[GP_NODES * D];      // 8 KB
    const int t   = threadIdx.x;
    const int nb0 = blockIdx.x * GP_NODES;
    const float4* src4 = (const float4*)(hin + (size_t)nb0 * D);
    float4* dst4 = (float4*)xt;
    if (nb0 + GP_NODES <= NN) {
        dst4[t]       = src4[t];
        dst4[t + 256] = src4[t + 256];
    } else {
        #pragma unroll
        for (int i = 0; i < 2; ++i) {
            const int idx = t + 256 * i;
            const int node = nb0 + (idx >> 4);
            dst4[idx] = (node < NN) ? src4[idx] : make_float4(0.f, 0.f, 0.f, 0.f);
        }
    }
    __syncthreads();

    const int wv   = t >> 6;
    const int lane = t & 63;
    const float* xw = xt + wv * 8 * D;      // this wave's 8 node rows

    float accs[8], accl[8], accd[HASD ? 8 : 1];
    #pragma unroll
    for (int m = 0; m < 8; ++m) { accs[m] = 0.f; accl[m] = 0.f; }
    if (HASD) {
        #pragma unroll
        for (int m = 0; m < 8; ++m) accd[m] = 0.f;
    }

    #pragma unroll 4
    for (int k = 0; k < D; k += 4) {
        float ws[4], wl[4], wd[4];
        #pragma unroll
        for (int j = 0; j < 4; ++j) {
            ws[j] = Wsrc[(k + j) * D + lane];
            wl[j] = Wlin[(k + j) * D + lane];
            if (HASD) wd[j] = Wdst[(k + j) * D + lane];
        }
        #pragma unroll
        for (int m = 0; m < 8; ++m) {
            const float4 xm = *(const float4*)(xw + m * D + k);  // LDS broadcast
            accs[m] = fmaf(xm.x, ws[0], accs[m]);
            accs[m] = fmaf(xm.y, ws[1], accs[m]);
            accs[m] = fmaf(xm.z, ws[2], accs[m]);
            accs[m] = fmaf(xm.w, ws[3], accs[m]);
            accl[m] = fmaf(xm.x, wl[0], accl[m]);
            accl[m] = fmaf(xm.y, wl[1], accl[m]);
            accl[m] = fmaf(xm.z, wl[2], accl[m]);
            accl[m] = fmaf(xm.w, wl[3], accl[m]);
            if (HASD) {
                accd[m] = fmaf(xm.x, wd[0], accd[m]);
                accd[m] = fmaf(xm.y, wd[1], accd[m]);
                accd[m] = fmaf(xm.z, wd[2], accd[m]);
                accd[m] = fmaf(xm.w, wd[3], accd[m]);
            }
        }
    }

    const float avs_l = avs[lane], avd_l = avd[lane];
    const float bias  = blin[lane] + bgat[lane];
    #pragma unroll
    for (int m = 0; m < 8; ++m) {
        const int node = nb0 + wv * 8 + m;
        const float vs = waveReduceSum(accs[m] * avs_l);
        const float vd = waveReduceSum((HASD ? accd[m] : accs[m]) * avd_l);
        if (node < NN) {
            hp[(size_t)node * D + lane]  = __float2bfloat16(accs[m]);
            agg[(size_t)node * D + lane] = accl[m] + bias;
            if (lane == 0) {
                alpha_s[node] = vs;
                alpha_d[node] = vd;
            }
        }
    }
}

// ---------------------------------------------------------------------------
// CSR-by-destination: fixed-capacity bucket layout.
// ---------------------------------------------------------------------------
__global__ void zero_ints(int* __restrict__ p, int n) {
    const int i = blockIdx.x * blockDim.x + threadIdx.x;
    if (i < n) p[i] = 0;
}

__global__ __launch_bounds__(256) void bucket_partition(const int* __restrict__ ei,
                                                        int* __restrict__ bcur,
                                                        int2* __restrict__ pairs) {
    __shared__ int h[NBUK];
    __shared__ int cur[NBUK];
    for (int i = threadIdx.x; i < NBUK; i += 256) h[i] = 0;
    __syncthreads();
    const int base = blockIdx.x * EPB;
    const int lim  = min(EPB, NE - base);
    for (int i = threadIdx.x; i < lim; i += 256)
        atomicAdd(&h[ei[NE + base + i] >> BSH], 1);
    __syncthreads();
    for (int i = threadIdx.x; i < NBUK; i += 256) {
        const int c = h[i];
        cur[i] = c ? atomicAdd(&bcur[i], c) : 0;
    }
    __syncthreads();
    for (int i = threadIdx.x; i < lim; i += 256) {
        const int s = ei[base + i];
        const int d = ei[NE + base + i];
        const int b = d >> BSH;
        const int pos = atomicAdd(&cur[b], 1);
        if (pos < BCAP) pairs[(b << BCAPSH) + pos] = make_int2(s, d);
    }
}

__global__ __launch_bounds__(256) void csr_finalize(const int2* __restrict__ pairs,
                                                    const int* __restrict__ bcur,
                                                    int* __restrict__ cnt,
                                                    int* __restrict__ row_start,
                                                    int* __restrict__ csr_src) {
    __shared__ int ncnt[64];
    __shared__ int lsrc[BCAP];
    const int t = threadIdx.x;
    const int b = blockIdx.x;
    const int beg = b << BCAPSH;
    const int m = min(bcur[b], BCAP);
    const int nbase = b << BSH;
    if (t < 64) ncnt[t] = 0;
    __syncthreads();
    for (int i = t; i < m; i += 256)
        atomicAdd(&ncnt[pairs[beg + i].y - nbase], 1);
    __syncthreads();
    if (t < 64) {
        const int v = ncnt[t];
        int inc = v;
        #pragma unroll
        for (int off = 1; off < 64; off <<= 1) {
            const int u = __shfl_up(inc, off, 64);
            if (t >= off) inc += u;
        }
        const int excl = inc - v;
        if (nbase + t < NN) {
            cnt[nbase + t] = v;
            row_start[nbase + t] = beg + excl;
        }
        ncnt[t] = excl;   // becomes bucket-local cursor
    }
    __syncthreads();
    for (int i = t; i < m; i += 256) {
        const int2 p = pairs[beg + i];
        const int pos = atomicAdd(&ncnt[p.y - nbase], 1);
        lsrc[pos] = p.x;
    }
    __syncthreads();
    for (int i = t; i < m; i += 256)
        csr_src[beg + i] = lsrc[i];
}

// ---------------------------------------------------------------------------
// GAT pass 1 (lo): softmax + write per-edge weights + aggregate channels 0-31.
// hp rows are 128B = 2 lines; this pass touches only even lines (3.2 MB
// footprint < 4 MB L2/XCD -> gathers stay L2-resident). Streaming accesses
// (csr, wbuf, agg) use non-temporal hints to keep hp lines hot.
// Quad layout: quad q handles edge j+q, lane-in-quad c handles channels
// {2c,2c+1} -> 4 edges / 4x64B lines per instruction.
// ---------------------------------------------------------------------------
template <bool DO_RELU, bool DO_STATS>
__global__ __launch_bounds__(256) void gat_half_lo(
                         const int* __restrict__ csr_src,
                         const int* __restrict__ row_start,
                         const int* __restrict__ cnt,
                         const float* __restrict__ as,
                         const float* __restrict__ ad,
                         const __hip_bfloat16* __restrict__ hp,
                         float* __restrict__ agg,
                         float* __restrict__ wbuf,
                         float* __restrict__ partial) {
    __shared__ int2 esm[4][KMAX * 64];
    const int wv   = threadIdx.x >> 6;
    const int lane = threadIdx.x & 63;
    const int node = blockIdx.x * 4 + wv;   // NN == 4*GAT_BLOCKS: always valid
    const int snode = __builtin_amdgcn_readfirstlane(node);
    const int deg = cnt[snode];
    const int rs  = row_start[snode];
    const int quad = lane >> 4;
    const int c    = lane & 15;
    float2 acc = make_float2(0.f, 0.f);
    if (deg > 0) {
        const float ad_d = ad[snode];
        int   sr[KMAX];
        float ea[KMAX];
        float mx = -INFINITY;
        #pragma unroll
        for (int k = 0; k < KMAX; ++k) {
            const int j = k * 64 + lane;
            const bool valid = j < deg;
            const int s = valid ? __builtin_nontemporal_load(csr_src + rs + j) : 0;
            float a = valid ? (as[s] + ad_d) : -INFINITY;
            a = (a >= 0.f) ? a : NEG_SLOPE * a;
            sr[k] = s;
            ea[k] = a;
            mx = fmaxf(mx, a);
        }
        mx = waveReduceMax(mx);
        float sum = 0.f;
        #pragma unroll
        for (int k = 0; k < KMAX; ++k) {
            float e = __expf(ea[k] - mx);
            e = (k * 64 + lane < deg) ? e : 0.f;
            ea[k] = e;
            sum += e;
        }
        sum = waveReduceSum(sum);
        const float inv = 1.f / (sum + EPS_SM);
        #pragma unroll
        for (int k = 0; k < KMAX; ++k) {
            if (k * 64 < deg) {          // wave-uniform
                const int j = k * 64 + lane;
                const float w = ea[k] * inv;
                if (j < deg) __builtin_nontemporal_store(w, wbuf + rs + j);
                esm[wv][j] = make_int2(sr[k] * 32, __float_as_int(w));  // pads get w=0
            }
        }
        const unsigned* hp32 = (const unsigned*)hp;
        const int jmax = (deg + 3) & ~3;
        float2 a0 = make_float2(0.f, 0.f), a1 = make_float2(0.f, 0.f);
        int j = 0;
        for (; j + 8 <= jmax; j += 8) {
            const int2 p0 = esm[wv][j + quad];
            const int2 p1 = esm[wv][j + 4 + quad];
            const unsigned v0 = hp32[p0.x + c];
            const unsigned v1 = hp32[p1.x + c];
            const float w0 = __int_as_float(p0.y), w1 = __int_as_float(p1.y);
            a0.x = fmaf(w0, bflo(v0), a0.x);
            a0.y = fmaf(w0, bfhi(v0), a0.y);
            a1.x = fmaf(w1, bflo(v1), a1.x);
            a1.y = fmaf(w1, bfhi(v1), a1.y);
        }
        for (; j < jmax; j += 4) {
            const int2 p = esm[wv][j + quad];
            const unsigned v = hp32[p.x + c];
            const float w = __int_as_float(p.y);
            a0.x = fmaf(w, bflo(v), a0.x);
            a0.y = fmaf(w, bfhi(v), a0.y);
        }
        acc.x = a0.x + a1.x;
        acc.y = a0.y + a1.y;
    }
    acc.x += __shfl_xor(acc.x, 16, 64);
    acc.y += __shfl_xor(acc.y, 16, 64);
    acc.x += __shfl_xor(acc.x, 32, 64);
    acc.y += __shfl_xor(acc.y, 32, 64);

    float2 r2 = make_float2(0.f, 0.f);
    if (quad == 0) {
        unsigned long long g = __builtin_nontemporal_load(
            (const unsigned long long*)(agg + (size_t)node * D + 2 * c));
        r2.x = __uint_as_float((unsigned)g) + acc.x;
        r2.y = __uint_as_float((unsigned)(g >> 32)) + acc.y;
        if (DO_RELU) { r2.x = fmaxf(r2.x, 0.f); r2.y = fmaxf(r2.y, 0.f); }
        const unsigned long long o = (unsigned long long)__float_as_uint(r2.x) |
                                     ((unsigned long long)__float_as_uint(r2.y) << 32);
        __builtin_nontemporal_store(o, (unsigned long long*)(agg + (size_t)node * D + 2 * c));
    }
    if (DO_STATS) {
        float s  = r2.x + r2.y;
        float ss = r2.x * r2.x + r2.y * r2.y;
        s  = waveReduceSum(s);
        ss = waveReduceSum(ss);
        __shared__ float red[2][4];
        if (lane == 0) { red[0][wv] = s; red[1][wv] = ss; }
        __syncthreads();
        if (threadIdx.x == 0) {
            partial[blockIdx.x]              = red[0][0] + red[0][1] + red[0][2] + red[0][3];
            partial[GAT_BLOCKS + blockIdx.x] = red[1][0] + red[1][1] + red[1][2] + red[1][3];
        }
    }
}

// ---------------------------------------------------------------------------
// GAT pass 2 (hi): re-stage csr+w, aggregate channels 32-63 (odd lines only).
// ---------------------------------------------------------------------------
template <bool DO_RELU, bool DO_STATS>
__global__ __launch_bounds__(256) void gat_half_hi(
                         const int* __restrict__ csr_src,
                         const int* __restrict__ row_start,
                         const int* __restrict__ cnt,
                         const float* __restrict__ wbuf,
                         const __hip_bfloat16* __restrict__ hp,
                         float* __restrict__ agg,
                         float* __restrict__ partial) {
    __shared__ int2 esm[4][KMAX * 64];
    const int wv   = threadIdx.x >> 6;
    const int lane = threadIdx.x & 63;
    const int node = blockIdx.x * 4 + wv;
    const int snode = __builtin_amdgcn_readfirstlane(node);
    const int deg = cnt[snode];
    const int rs  = row_start[snode];
    const int quad = lane >> 4;
    const int c    = lane & 15;
    float2 acc = make_float2(0.f, 0.f);
    if (deg > 0) {
        #pragma unroll
        for (int k = 0; k < KMAX; ++k) {
            if (k * 64 < deg) {          // wave-uniform
                const int j = k * 64 + lane;
                const bool valid = j < deg;
                const int   s = valid ? __builtin_nontemporal_load(csr_src + rs + j) : 0;
                const float w = valid ? __builtin_nontemporal_load(wbuf + rs + j) : 0.f;
                esm[wv][j] = make_int2(s * 32, __float_as_int(w));
            }
        }
        const unsigned* hp32 = (const unsigned*)hp;
        const int jmax = (deg + 3) & ~3;
        float2 a0 = make_float2(0.f, 0.f), a1 = make_float2(0.f, 0.f);
        int j = 0;
        for (; j + 8 <= jmax; j += 8) {
            const int2 p0 = esm[wv][j + quad];
            const int2 p1 = esm[wv][j + 4 + quad];
            const unsigned v0 = hp32[p0.x + 16 + c];
            const unsigned v1 = hp32[p1.x + 16 + c];
            const float w0 = __int_as_float(p0.y), w1 = __int_as_float(p1.y);
            a0.x = fmaf(w0, bflo(v0), a0.x);
            a0.y = fmaf(w0, bfhi(v0), a0.y);
            a1.x = fmaf(w1, bflo(v1), a1.x);
            a1.y = fmaf(w1, bfhi(v1), a1.y);
        }
        for (; j < jmax; j += 4) {
            const int2 p = esm[wv][j + quad];
            const unsigned v = hp32[p.x + 16 + c];
            const float w = __int_as_float(p.y);
            a0.x = fmaf(w, bflo(v), a0.x);
            a0.y = fmaf(w, bfhi(v), a0.y);
        }
        acc.x = a0.x + a1.x;
        acc.y = a0.y + a1.y;
    }
    acc.x += __shfl_xor(acc.x, 16, 64);
    acc.y += __shfl_xor(acc.y, 16, 64);
    acc.x += __shfl_xor(acc.x, 32, 64);
    acc.y += __shfl_xor(acc.y, 32, 64);

    float2 r2 = make_float2(0.f, 0.f);
    if (quad == 0) {
        unsigned long long g = __builtin_nontemporal_load(
            (const unsigned long long*)(agg + (size_t)node * D + 32 + 2 * c));
        r2.x = __uint_as_float((unsigned)g) + acc.x;
        r2.y = __uint_as_float((unsigned)(g >> 32)) + acc.y;
        if (DO_RELU) { r2.x = fmaxf(r2.x, 0.f); r2.y = fmaxf(r2.y, 0.f); }
        const unsigned long long o = (unsigned long long)__float_as_uint(r2.x) |
                                     ((unsigned long long)__float_as_uint(r2.y) << 32);
        __builtin_nontemporal_store(o, (unsigned long long*)(agg + (size_t)node * D + 32 + 2 * c));
    }
    if (DO_STATS) {
        float s  = r2.x + r2.y;
        float ss = r2.x * r2.x + r2.y * r2.y;
        s  = waveReduceSum(s);
        ss = waveReduceSum(ss);
        __shared__ float red[2][4];
        if (lane == 0) { red[0][wv] = s; red[1][wv] = ss; }
        __syncthreads();
        if (threadIdx.x == 0) {
            partial[blockIdx.x]              = red[0][0] + red[0][1] + red[0][2] + red[0][3];
            partial[GAT_BLOCKS + blockIdx.x] = red[1][0] + red[1][1] + red[1][2] + red[1][3];
        }
    }
}

// ---------------------------------------------------------------------------
// LN partial reduce + final normalize/project
// ---------------------------------------------------------------------------
__global__ void ln_reduce(const float* __restrict__ partial, float* __restrict__ stats) {
    float s = 0.f, ss = 0.f;
    for (int i = threadIdx.x; i < GAT_BLOCKS; i += 256) {
        s  += partial[i] + partial[2 * GAT_BLOCKS + i];
        ss += partial[GAT_BLOCKS + i] + partial[3 * GAT_BLOCKS + i];
    }
    s  = waveReduceSum(s);
    ss = waveReduceSum(ss);
    __shared__ float sm[2][4];
    if ((threadIdx.x & 63) == 0) {
        sm[0][threadIdx.x >> 6] = s;
        sm[1][threadIdx.x >> 6] = ss;
    }
    __syncthreads();
    if (threadIdx.x == 0) {
        stats[0] = sm[0][0] + sm[0][1] + sm[0][2] + sm[0][3];
        stats[1] = sm[1][0] + sm[1][1] + sm[1][2] + sm[1][3];
    }
}

__global__ void finalize(const float* __restrict__ x,
                         const float* __restrict__ stats,
                         const float* __restrict__ lnw,
                         const float* __restrict__ lnb,
                         const float* __restrict__ pw,
                         const float* __restrict__ pb,
                         float* __restrict__ out) {
    const int wave = (blockIdx.x * blockDim.x + threadIdx.x) >> 6;
    const int lane = threadIdx.x & 63;
    if (wave >= NN) return;
    const float inv_nd = 1.f / (float)(NN * D);
    const float mu  = stats[0] * inv_nd;
    const float var = stats[1] * inv_nd - mu * mu;
    const float rs = rsqrtf(var + EPS_LN);
    const float v = x[(size_t)wave * D + lane];
    const float xn = (v - mu) * rs * lnw[lane] + lnb[lane];
    const float c = waveReduceSum(xn * pw[lane]);
    if (lane == 0) out[wave] = c + pb[0];
}

extern "C" void kernel_launch(void* const* d_in, const int* in_sizes, int n_in,
                              void* d_out, int out_size, void* d_ws, size_t ws_size,
                              hipStream_t stream) {
    const float* x     = (const float*)d_in[0];
    const int*   ei    = (const int*)d_in[1];
    const float* Wsrc0 = (const float*)d_in[2];
    const float* Wdst0 = (const float*)d_in[3];
    const float* asrc0 = (const float*)d_in[4];
    const float* adst0 = (const float*)d_in[5];
    const float* b0    = (const float*)d_in[6];
    const float* linW0 = (const float*)d_in[7];
    const float* linb0 = (const float*)d_in[8];
    const float* W1    = (const float*)d_in[9];
    const float* asrc1 = (const float*)d_in[10];
    const float* adst1 = (const float*)d_in[11];
    const float* b1    = (const float*)d_in[12];
    const float* linW1 = (const float*)d_in[13];
    const float* linb1 = (const float*)d_in[14];
    const float* W2    = (const float*)d_in[15];
    const float* asrc2 = (const float*)d_in[16];
    const float* adst2 = (const float*)d_in[17];
    const float* b2    = (const float*)d_in[18];
    const float* linW2 = (const float*)d_in[19];
    const float* linb2 = (const float*)d_in[20];
    const float* lnw   = (const float*)d_in[21];
    const float* lnb   = (const float*)d_in[22];
    const float* pW    = (const float*)d_in[23];
    const float* pb    = (const float*)d_in[24];
    float* out = (float*)d_out;

    // workspace layout (pairs aliases A: pairs dead before layer-0 gemm writes A)
    int*   csr_src   = (int*)d_ws;                     // NBUK*BCAP
    float* wbuf      = (float*)(csr_src + NBUK * BCAP); // NBUK*BCAP
    int*   cnt       = (int*)(wbuf + NBUK * BCAP);     // NN
    int*   row_start = cnt + NN;                       // NN
    int*   bcur      = row_start + NN;                 // NBUK
    size_t off = (size_t)(2 * NBUK * BCAP + 2 * NN + NBUK);
    off = (off + 3) & ~(size_t)3;                      // 16 B align
    float* A     = (float*)d_ws + off;                 // NN*D floats
    int2*  pairs = (int2*)A;                           // NBUK*BCAP int2 (covers A)
    float* B     = A + (size_t)NBUK * BCAP * 2;        // after pairs extent
    __hip_bfloat16* P = (__hip_bfloat16*)(B + NN * D); // NN*D bf16
    float* alpha_s = (float*)(P + NN * D);             // NN
    float* alpha_d = alpha_s + NN;                     // NN
    float* stats   = alpha_d + NN;                     // 2
    float* partial = stats + 2;                        // 4*GAT_BLOCKS

    const int elem_blocks = (NN * D) / 256;            // 12500

    // ---- build CSR by destination (bucket-strided; reused by all 3 layers) ----
    zero_ints<<<(NBUK + 255) / 256, 256, 0, stream>>>(bcur, NBUK);
    bucket_partition<<<NPB, 256, 0, stream>>>(ei, bcur, pairs);
    csr_finalize<<<NBUK, 256, 0, stream>>>(pairs, bcur, cnt, row_start, csr_src);

    // ---- layer 0 ----
    gemm_proj<true><<<GP_BLOCKS, 256, 0, stream>>>(x, Wsrc0, Wdst0, linW0, asrc0, adst0,
                                                   b0, linb0, P, A, alpha_s, alpha_d);
    gat_half_lo<true, false><<<GAT_BLOCKS, 256, 0, stream>>>(csr_src, row_start, cnt,
                                                  alpha_s, alpha_d, P, A, wbuf, partial);
    gat_half_hi<true, false><<<GAT_BLOCKS, 256, 0, stream>>>(csr_src, row_start, cnt,
                                                  wbuf, P, A, partial + 2 * GAT_BLOCKS);

    // ---- layer 1 ----
    gemm_proj<false><<<GP_BLOCKS, 256, 0, stream>>>(A, W1, W1, linW1, asrc1, adst1,
                                                    b1, linb1, P, B, alpha_s, alpha_d);
    gat_half_lo<true, false><<<GAT_BLOCKS, 256, 0, stream>>>(csr_src, row_start, cnt,
                                                  alpha_s, alpha_d, P, B, wbuf, partial);
    gat_half_hi<true, false><<<GAT_BLOCKS, 256, 0, stream>>>(csr_src, row_start, cnt,
                                                  wbuf, P, B, partial + 2 * GAT_BLOCKS);

    // ---- layer 2 (fused LN partials) ----
    gemm_proj<false><<<GP_BLOCKS, 256, 0, stream>>>(B, W2, W2, linW2, asrc2, adst2,
                                                    b2, linb2, P, A, alpha_s, alpha_d);
    gat_half_lo<false, true><<<GAT_BLOCKS, 256, 0, stream>>>(csr_src, row_start, cnt,
                                                  alpha_s, alpha_d, P, A, wbuf, partial);
    gat_half_hi<false, true><<<GAT_BLOCKS, 256, 0, stream>>>(csr_src, row_start, cnt,
                                                  wbuf, P, A, partial + 2 * GAT_BLOCKS);

    // ---- graph layernorm + projection ----
    ln_reduce<<<1, 256, 0, stream>>>(partial, stats);
    finalize<<<elem_blocks, 256, 0, stream>>>(A, stats, lnw, lnb, pW, pb, out);
}

// Round 9
// 362.819 us; speedup vs baseline: 1.2151x; 1.2151x over previous
//
#include <hip/hip_runtime.h>
#include <hip/hip_bf16.h>

#define NN 50000
#define NE 1200000
#define D 64
#define NEG_SLOPE 0.2f
#define EPS_SM 1e-16f
#define EPS_LN 1e-5f
#define KMAX 4            // supports degree <= 256; Poisson(24) max over 50k nodes ~55
#define BSH 6             // 64 nodes per bucket
#define NBUK 782          // ceil(50000/64)
#define BCAP 2048         // fixed bucket capacity (mean 1536, +13 sigma)
#define BCAPSH 11
#define EPB 4096          // edges per partition block
#define NPB 293           // ceil(NE/EPB)
#define GP_NODES 32
#define GP_BLOCKS 1563    // ceil(50000/32)
#define GAT_BLOCKS 12500  // NN/4 exactly

__device__ __forceinline__ float waveReduceSum(float v) {
    #pragma unroll
    for (int off = 32; off > 0; off >>= 1)
        v += __shfl_xor(v, off, 64);
    return v;
}
__device__ __forceinline__ float waveReduceMax(float v) {
    #pragma unroll
    for (int off = 32; off > 0; off >>= 1)
        v = fmaxf(v, __shfl_xor(v, off, 64));
    return v;
}
__device__ __forceinline__ float bflo(unsigned v) { return __uint_as_float(v << 16); }
__device__ __forceinline__ float bfhi(unsigned v) { return __uint_as_float(v & 0xffff0000u); }

// ---------------------------------------------------------------------------
// Per-node projections + attention logits. 32 nodes/block, 8 nodes/wave.
// ---------------------------------------------------------------------------
template <bool HASD>
__global__ __launch_bounds__(256) void gemm_proj(
                          const float* __restrict__ hin,
                          const float* __restrict__ Wsrc,
                          const float* __restrict__ Wdst,
                          const float* __restrict__ Wlin,
                          const float* __restrict__ avs,
                          const float* __restrict__ avd,
                          const float* __restrict__ bgat,
                          const float* __restrict__ blin,
                          __hip_bfloat16* __restrict__ hp,
                          float* __restrict__ agg,
                          float* __restrict__ alpha_s,
                          float* __restrict__ alpha_d) {
    __shared__ float xt[GP_NODES * D];      // 8 KB
    const int t   = threadIdx.x;
    const int nb0 = blockIdx.x * GP_NODES;
    const float4* src4 = (const float4*)(hin + (size_t)nb0 * D);
    float4* dst4 = (float4*)xt;
    if (nb0 + GP_NODES <= NN) {
        dst4[t]       = src4[t];
        dst4[t + 256] = src4[t + 256];
    } else {
        #pragma unroll
        for (int i = 0; i < 2; ++i) {
            const int idx = t + 256 * i;
            const int node = nb0 + (idx >> 4);
            dst4[idx] = (node < NN) ? src4[idx] : make_float4(0.f, 0.f, 0.f, 0.f);
        }
    }
    __syncthreads();

    const int wv   = t >> 6;
    const int lane = t & 63;
    const float* xw = xt + wv * 8 * D;      // this wave's 8 node rows

    float accs[8], accl[8], accd[HASD ? 8 : 1];
    #pragma unroll
    for (int m = 0; m < 8; ++m) { accs[m] = 0.f; accl[m] = 0.f; }
    if (HASD) {
        #pragma unroll
        for (int m = 0; m < 8; ++m) accd[m] = 0.f;
    }

    #pragma unroll 4
    for (int k = 0; k < D; k += 4) {
        float ws[4], wl[4], wd[4];
        #pragma unroll
        for (int j = 0; j < 4; ++j) {
            ws[j] = Wsrc[(k + j) * D + lane];
            wl[j] = Wlin[(k + j) * D + lane];
            if (HASD) wd[j] = Wdst[(k + j) * D + lane];
        }
        #pragma unroll
        for (int m = 0; m < 8; ++m) {
            const float4 xm = *(const float4*)(xw + m * D + k);  // LDS broadcast
            accs[m] = fmaf(xm.x, ws[0], accs[m]);
            accs[m] = fmaf(xm.y, ws[1], accs[m]);
            accs[m] = fmaf(xm.z, ws[2], accs[m]);
            accs[m] = fmaf(xm.w, ws[3], accs[m]);
            accl[m] = fmaf(xm.x, wl[0], accl[m]);
            accl[m] = fmaf(xm.y, wl[1], accl[m]);
            accl[m] = fmaf(xm.z, wl[2], accl[m]);
            accl[m] = fmaf(xm.w, wl[3], accl[m]);
            if (HASD) {
                accd[m] = fmaf(xm.x, wd[0], accd[m]);
                accd[m] = fmaf(xm.y, wd[1], accd[m]);
                accd[m] = fmaf(xm.z, wd[2], accd[m]);
                accd[m] = fmaf(xm.w, wd[3], accd[m]);
            }
        }
    }

    const float avs_l = avs[lane], avd_l = avd[lane];
    const float bias  = blin[lane] + bgat[lane];
    #pragma unroll
    for (int m = 0; m < 8; ++m) {
        const int node = nb0 + wv * 8 + m;
        const float vs = waveReduceSum(accs[m] * avs_l);
        const float vd = waveReduceSum((HASD ? accd[m] : accs[m]) * avd_l);
        if (node < NN) {
            hp[(size_t)node * D + lane]  = __float2bfloat16(accs[m]);
            agg[(size_t)node * D + lane] = accl[m] + bias;
            if (lane == 0) {
                alpha_s[node] = vs;
                alpha_d[node] = vd;
            }
        }
    }
}

// ---------------------------------------------------------------------------
// CSR-by-destination: fixed-capacity bucket layout.
// ---------------------------------------------------------------------------
__global__ __launch_bounds__(256) void bucket_partition(const int* __restrict__ ei,
                                                        int* __restrict__ bcur,
                                                        int2* __restrict__ pairs) {
    __shared__ int h[NBUK];
    __shared__ int cur[NBUK];
    for (int i = threadIdx.x; i < NBUK; i += 256) h[i] = 0;
    __syncthreads();
    const int base = blockIdx.x * EPB;
    const int lim  = min(EPB, NE - base);
    for (int i = threadIdx.x; i < lim; i += 256)
        atomicAdd(&h[ei[NE + base + i] >> BSH], 1);
    __syncthreads();
    for (int i = threadIdx.x; i < NBUK; i += 256) {
        const int c = h[i];
        cur[i] = c ? atomicAdd(&bcur[i], c) : 0;
    }
    __syncthreads();
    for (int i = threadIdx.x; i < lim; i += 256) {
        const int s = ei[base + i];
        const int d = ei[NE + base + i];
        const int b = d >> BSH;
        const int pos = atomicAdd(&cur[b], 1);
        if (pos < BCAP) pairs[(b << BCAPSH) + pos] = make_int2(s, d);
    }
}

__global__ __launch_bounds__(256) void csr_finalize(const int2* __restrict__ pairs,
                                                    const int* __restrict__ bcur,
                                                    int* __restrict__ cnt,
                                                    int* __restrict__ row_start,
                                                    int* __restrict__ csr_src) {
    __shared__ int ncnt[64];
    __shared__ int lsrc[BCAP];
    const int t = threadIdx.x;
    const int b = blockIdx.x;
    const int beg = b << BCAPSH;
    const int m = min(bcur[b], BCAP);
    const int nbase = b << BSH;
    if (t < 64) ncnt[t] = 0;
    __syncthreads();
    for (int i = t; i < m; i += 256)
        atomicAdd(&ncnt[pairs[beg + i].y - nbase], 1);
    __syncthreads();
    if (t < 64) {
        const int v = ncnt[t];
        int inc = v;
        #pragma unroll
        for (int off = 1; off < 64; off <<= 1) {
            const int u = __shfl_up(inc, off, 64);
            if (t >= off) inc += u;
        }
        const int excl = inc - v;
        if (nbase + t < NN) {
            cnt[nbase + t] = v;
            row_start[nbase + t] = beg + excl;
        }
        ncnt[t] = excl;   // becomes bucket-local cursor
    }
    __syncthreads();
    for (int i = t; i < m; i += 256) {
        const int2 p = pairs[beg + i];
        const int pos = atomicAdd(&ncnt[p.y - nbase], 1);
        lsrc[pos] = p.x;
    }
    __syncthreads();
    for (int i = t; i < m; i += 256)
        csr_src[beg + i] = lsrc[i];
}

// ---------------------------------------------------------------------------
// Fused per-node GAT. Aggregation: lanes 0-31 process edge j (2 channels per
// lane via one uint = 2 bf16), lanes 32-63 edge j+1. 16-edge unroll keeps
// 8 gathers outstanding (MLP). Cross-half combine via shfl_xor(32).
// DO_STATS variant (layer 2) also emits per-block LN partial sums.
// ---------------------------------------------------------------------------
template <bool DO_RELU, bool DO_STATS>
__global__ __launch_bounds__(256) void gat_node(
                         const int* __restrict__ csr_src,
                         const int* __restrict__ row_start,
                         const int* __restrict__ cnt,
                         const float* __restrict__ as,
                         const float* __restrict__ ad,
                         const __hip_bfloat16* __restrict__ hp,
                         float* __restrict__ agg,
                         float* __restrict__ partial) {
    __shared__ int2 esm[4][KMAX * 64];
    const int wv   = threadIdx.x >> 6;
    const int lane = threadIdx.x & 63;
    const int node = blockIdx.x * 4 + wv;   // NN == 4*GAT_BLOCKS: always valid
    const int snode = __builtin_amdgcn_readfirstlane(node);
    const int deg = cnt[snode];
    const int rs  = row_start[snode];
    const int half = lane >> 5;             // which edge of the pair
    const int c2   = lane & 31;             // channel-pair index
    float2 acc = make_float2(0.f, 0.f);
    if (deg > 0) {
        const float ad_d = ad[snode];
        int   sr[KMAX];
        float ea[KMAX];
        float mx = -INFINITY;
        #pragma unroll
        for (int k = 0; k < KMAX; ++k) {
            const int j = k * 64 + lane;
            const bool valid = j < deg;
            const int s = valid ? csr_src[rs + j] : 0;
            float a = valid ? (as[s] + ad_d) : -INFINITY;
            a = (a >= 0.f) ? a : NEG_SLOPE * a;
            sr[k] = s;
            ea[k] = a;
            mx = fmaxf(mx, a);
        }
        mx = waveReduceMax(mx);
        float sum = 0.f;
        #pragma unroll
        for (int k = 0; k < KMAX; ++k) {
            float e = __expf(ea[k] - mx);
            e = (k * 64 + lane < deg) ? e : 0.f;   // invalid lanes -> w = 0 (pads)
            ea[k] = e;
            sum += e;
        }
        sum = waveReduceSum(sum);
        const float inv = 1.f / (sum + EPS_SM);
        #pragma unroll
        for (int k = 0; k < KMAX; ++k) {
            if (k * 64 < deg)            // wave-uniform; lanes >= deg write {0,0}
                esm[wv][k * 64 + lane] = make_int2(sr[k] * 32, __float_as_int(ea[k] * inv));
        }
        // same-wave LDS write->read: compiler orders via lgkmcnt
        const unsigned* hp32 = (const unsigned*)hp;
        const int jmax = (deg + 1) & ~1;   // odd deg: entry [deg] is a {0,0} pad
        float2 a0 = make_float2(0.f, 0.f), a1 = make_float2(0.f, 0.f);
        int j = 0;
        for (; j + 16 <= jmax; j += 16) {
            int2 p[8];
            unsigned v[8];
            #pragma unroll
            for (int u = 0; u < 8; ++u) p[u] = esm[wv][j + 2 * u + half];
            #pragma unroll
            for (int u = 0; u < 8; ++u) v[u] = hp32[p[u].x + c2];
            #pragma unroll
            for (int u = 0; u < 8; ++u) {
                const float w = __int_as_float(p[u].y);
                if (u & 1) {
                    a1.x = fmaf(w, bflo(v[u]), a1.x);
                    a1.y = fmaf(w, bfhi(v[u]), a1.y);
                } else {
                    a0.x = fmaf(w, bflo(v[u]), a0.x);
                    a0.y = fmaf(w, bfhi(v[u]), a0.y);
                }
            }
        }
        for (; j + 4 <= jmax; j += 4) {
            const int2 p0 = esm[wv][j + 0 + half];
            const int2 p1 = esm[wv][j + 2 + half];
            const unsigned v0 = hp32[p0.x + c2];
            const unsigned v1 = hp32[p1.x + c2];
            const float w0 = __int_as_float(p0.y), w1 = __int_as_float(p1.y);
            a0.x = fmaf(w0, bflo(v0), a0.x);
            a0.y = fmaf(w0, bfhi(v0), a0.y);
            a1.x = fmaf(w1, bflo(v1), a1.x);
            a1.y = fmaf(w1, bfhi(v1), a1.y);
        }
        for (; j < jmax; j += 2) {
            const int2 p = esm[wv][j + half];
            const unsigned v = hp32[p.x + c2];
            const float w = __int_as_float(p.y);
            a0.x = fmaf(w, bflo(v), a0.x);
            a0.y = fmaf(w, bfhi(v), a0.y);
        }
        acc.x = a0.x + a1.x;
        acc.y = a0.y + a1.y;
    }
    acc.x += __shfl_xor(acc.x, 32, 64);
    acc.y += __shfl_xor(acc.y, 32, 64);

    float2 r2 = make_float2(0.f, 0.f);
    if (half == 0) {
        const float2 g = *(const float2*)(agg + (size_t)node * D + 2 * c2);
        r2.x = g.x + acc.x;
        r2.y = g.y + acc.y;
        if (DO_RELU) { r2.x = fmaxf(r2.x, 0.f); r2.y = fmaxf(r2.y, 0.f); }
        *(float2*)(agg + (size_t)node * D + 2 * c2) = r2;
    }
    if (DO_STATS) {
        float s  = r2.x + r2.y;                 // half==1 lanes contribute 0
        float ss = r2.x * r2.x + r2.y * r2.y;
        s  = waveReduceSum(s);
        ss = waveReduceSum(ss);
        __shared__ float red[2][4];
        if (lane == 0) { red[0][wv] = s; red[1][wv] = ss; }
        __syncthreads();
        if (threadIdx.x == 0) {
            partial[blockIdx.x]              = red[0][0] + red[0][1] + red[0][2] + red[0][3];
            partial[GAT_BLOCKS + blockIdx.x] = red[1][0] + red[1][1] + red[1][2] + red[1][3];
        }
    }
}

// ---------------------------------------------------------------------------
// LN partial reduce + final normalize/project
// ---------------------------------------------------------------------------
__global__ void ln_reduce(const float* __restrict__ partial, float* __restrict__ stats) {
    float s = 0.f, ss = 0.f;
    for (int i = threadIdx.x; i < GAT_BLOCKS; i += 256) {
        s  += partial[i];
        ss += partial[GAT_BLOCKS + i];
    }
    s  = waveReduceSum(s);
    ss = waveReduceSum(ss);
    __shared__ float sm[2][4];
    if ((threadIdx.x & 63) == 0) {
        sm[0][threadIdx.x >> 6] = s;
        sm[1][threadIdx.x >> 6] = ss;
    }
    __syncthreads();
    if (threadIdx.x == 0) {
        stats[0] = sm[0][0] + sm[0][1] + sm[0][2] + sm[0][3];
        stats[1] = sm[1][0] + sm[1][1] + sm[1][2] + sm[1][3];
    }
}

__global__ void finalize(const float* __restrict__ x,
                         const float* __restrict__ stats,
                         const float* __restrict__ lnw,
                         const float* __restrict__ lnb,
                         const float* __restrict__ pw,
                         const float* __restrict__ pb,
                         float* __restrict__ out) {
    const int wave = (blockIdx.x * blockDim.x + threadIdx.x) >> 6;
    const int lane = threadIdx.x & 63;
    if (wave >= NN) return;
    const float inv_nd = 1.f / (float)(NN * D);
    const float mu  = stats[0] * inv_nd;
    const float var = stats[1] * inv_nd - mu * mu;
    const float rs = rsqrtf(var + EPS_LN);
    const float v = x[(size_t)wave * D + lane];
    const float xn = (v - mu) * rs * lnw[lane] + lnb[lane];
    const float c = waveReduceSum(xn * pw[lane]);
    if (lane == 0) out[wave] = c + pb[0];
}

extern "C" void kernel_launch(void* const* d_in, const int* in_sizes, int n_in,
                              void* d_out, int out_size, void* d_ws, size_t ws_size,
                              hipStream_t stream) {
    const float* x     = (const float*)d_in[0];
    const int*   ei    = (const int*)d_in[1];
    const float* Wsrc0 = (const float*)d_in[2];
    const float* Wdst0 = (const float*)d_in[3];
    const float* asrc0 = (const float*)d_in[4];
    const float* adst0 = (const float*)d_in[5];
    const float* b0    = (const float*)d_in[6];
    const float* linW0 = (const float*)d_in[7];
    const float* linb0 = (const float*)d_in[8];
    const float* W1    = (const float*)d_in[9];
    const float* asrc1 = (const float*)d_in[10];
    const float* adst1 = (const float*)d_in[11];
    const float* b1    = (const float*)d_in[12];
    const float* linW1 = (const float*)d_in[13];
    const float* linb1 = (const float*)d_in[14];
    const float* W2    = (const float*)d_in[15];
    const float* asrc2 = (const float*)d_in[16];
    const float* adst2 = (const float*)d_in[17];
    const float* b2    = (const float*)d_in[18];
    const float* linW2 = (const float*)d_in[19];
    const float* linb2 = (const float*)d_in[20];
    const float* lnw   = (const float*)d_in[21];
    const float* lnb   = (const float*)d_in[22];
    const float* pW    = (const float*)d_in[23];
    const float* pb    = (const float*)d_in[24];
    float* out = (float*)d_out;

    // workspace layout (pairs aliases A: pairs dead before layer-0 gemm writes A)
    int*  csr_src   = (int*)d_ws;                    // NBUK*BCAP
    int*  cnt       = csr_src + NBUK * BCAP;         // NN
    int*  row_start = cnt + NN;                      // NN
    int*  bcur      = row_start + NN;                // NBUK
    size_t off = (size_t)(NBUK * BCAP + 2 * NN + NBUK);
    off = (off + 3) & ~(size_t)3;                    // 16 B align
    float* A     = (float*)d_ws + off;               // NN*D floats
    int2*  pairs = (int2*)A;                         // NBUK*BCAP int2 (covers A)
    float* B     = A + (size_t)NBUK * BCAP * 2;      // after pairs extent
    __hip_bfloat16* P = (__hip_bfloat16*)(B + NN * D);   // NN*D bf16
    float* alpha_s = (float*)(P + NN * D);           // NN
    float* alpha_d = alpha_s + NN;                   // NN
    float* stats   = alpha_d + NN;                   // 2
    float* partial = stats + 2;                      // 2*GAT_BLOCKS

    const int elem_blocks = (NN * D) / 256;          // 12500

    // ---- build CSR by destination (bucket-strided; reused by all 3 layers) ----
    hipMemsetAsync(bcur, 0, NBUK * sizeof(int), stream);
    bucket_partition<<<NPB, 256, 0, stream>>>(ei, bcur, pairs);
    csr_finalize<<<NBUK, 256, 0, stream>>>(pairs, bcur, cnt, row_start, csr_src);

    // ---- layer 0 ----
    gemm_proj<true><<<GP_BLOCKS, 256, 0, stream>>>(x, Wsrc0, Wdst0, linW0, asrc0, adst0,
                                                   b0, linb0, P, A, alpha_s, alpha_d);
    gat_node<true, false><<<GAT_BLOCKS, 256, 0, stream>>>(csr_src, row_start, cnt,
                                                          alpha_s, alpha_d, P, A, partial);

    // ---- layer 1 ----
    gemm_proj<false><<<GP_BLOCKS, 256, 0, stream>>>(A, W1, W1, linW1, asrc1, adst1,
                                                    b1, linb1, P, B, alpha_s, alpha_d);
    gat_node<true, false><<<GAT_BLOCKS, 256, 0, stream>>>(csr_src, row_start, cnt,
                                                          alpha_s, alpha_d, P, B, partial);

    // ---- layer 2 (fused LN partials) ----
    gemm_proj<false><<<GP_BLOCKS, 256, 0, stream>>>(B, W2, W2, linW2, asrc2, adst2,
                                                    b2, linb2, P, A, alpha_s, alpha_d);
    gat_node<false, true><<<GAT_BLOCKS, 256, 0, stream>>>(csr_src, row_start, cnt,
                                                          alpha_s, alpha_d, P, A, partial);

    // ---- graph layernorm + projection ----
    ln_reduce<<<1, 256, 0, stream>>>(partial, stats);
    finalize<<<elem_blocks, 256, 0, stream>>>(A, stats, lnw, lnb, pW, pb, out);
}